// Round 10
// baseline (291.088 us; speedup 1.0000x reference)
//
#include <hip/hip_runtime.h>
#include <hip/hip_bf16.h>
#include <hip/hip_fp16.h>

// GAT 2-layer forward. N=50000, E=800000 (+N self loops).
// L1: 128 -> 4x64 concat 256, ReLU.  L2: 256 -> 128, ReLU.
// R1: fused CSR softmax+aggregate.  R8: fp16 MFMA GEMMs.  R5: att_dots in
// GEMM epilogue.  R6: 4 nodes/256-thd agg.
// R15: aggs are gather-issue/latency bound -> R12 agg inner loop FROZEN.
// R18-R21: the 800K rank-atomics are a coherence-point RMW throughput floor
//  (~60us): insensitive to block ordering, 32x line padding, self-loop
//  removal, coupled/decoupled arrangement. STOP attacking; scatter stays
//  co-dispatched after gemm1 blocks.
// R22: the chain scatter/gemm1 -> agg1 -> gemm2 -> agg2 is serial; gemm2's
//  ~28us is fully exposed but tile g needs exactly agg1's rows 64g..64g+63.
//  FUSE agg1+gemm2: 1024-thr block per 64-node tile; phase 1 = frozen agg
//  loop (16 waves x 4 nodes, same 12.5K-wave parallelism), x2 -> LDS
//  ([64][264] padded vs 512B-stride bank conflict); barrier; phase 2 =
//  gemm2 MFMA from LDS A-frags. Deletes x2 global round-trip (51MB),
//  one dispatch gap, and 200K global att-dot atomics (LDS reduce).
//  h2 gets own buffer (h1 still gathered by late blocks while early
//  blocks write h2). 4 dispatches: pack_prep -> gemm1_scatter ->
//  agg1_gemm2 -> agg2.

#define NEG_SLOPE 0.2f

typedef __attribute__((ext_vector_type(8))) _Float16 f16x8;  // 8 fp16 = 4 VGPRs
typedef __attribute__((ext_vector_type(8))) short s16x8;
typedef __attribute__((ext_vector_type(4))) float f32x4;

// 16B load of 8 fp16 -> 8 fp32
__device__ inline void loadH8(float* v, const __half* p) {
    union { s16x8 raw; __half2 h2[4]; } u;
    u.raw = *(const s16x8*)p;
#pragma unroll
    for (int i = 0; i < 4; ++i) {
        float2 f = __half22float2(u.h2[i]);
        v[2 * i] = f.x;
        v[2 * i + 1] = f.y;
    }
}

// A-fragment loaders: fp16 direct, or fp32 with in-register convert.
__device__ inline f16x8 loadAfrag(const __half* __restrict__ p) {
    return *(const f16x8*)p;
}
__device__ inline f16x8 loadAfrag(const float* __restrict__ p) {
    float4 a = *(const float4*)p;
    float4 b = *(const float4*)(p + 4);
    union { f16x8 v; __half hv[8]; } u;
    u.hv[0] = __float2half(a.x); u.hv[1] = __float2half(a.y);
    u.hv[2] = __float2half(a.z); u.hv[3] = __float2half(a.w);
    u.hv[4] = __float2half(b.x); u.hv[5] = __float2half(b.y);
    u.hv[6] = __float2half(b.z); u.hv[7] = __float2half(b.w);
    return u.v;
}

// ---------------- pack W1/W2 + init cnt=1 + self-loop slot ----------------
// B-frag (16x16x32): lane l holds B[k0 + (l>>4)*8 + j][n0 + (l&15)], j=0..7.

__device__ inline void pack_w_elem(const float* __restrict__ W, __half* __restrict__ bp,
                                   int K, int N, int tid) {
    int k = tid / N, n = tid - k * N;
    int ks = k >> 5, k5 = k & 31, quad = k5 >> 3, j = k5 & 7;
    int ct = n >> 4;
    int lane = quad * 16 + (n & 15);
    size_t idx = ((size_t)(ct * (K >> 5) + ks) * 64 + lane) * 8 + j;
    bp[idx] = __float2half(W[tid]);
}

__global__ __launch_bounds__(256) void pack_prep(
        const float* __restrict__ W1, __half* __restrict__ bp1,
        const float* __restrict__ W2, __half* __restrict__ bp2,
        int* __restrict__ cnt, int* __restrict__ csr_src, int N) {
    int tid = blockIdx.x * blockDim.x + threadIdx.x;     // 32768 threads
    if (tid < 128 * 256) pack_w_elem(W1, bp1, 128, 256, tid);
    if (tid < 256 * 128) pack_w_elem(W2, bp2, 256, 128, tid);
    for (int n = tid; n < N; n += 32768) {
        cnt[n] = 1;                  // self-loop pre-counted
        csr_src[n << 6] = n;         // self-loop in slot 0
    }
}

// ---------------- fp16 MFMA GEMM body + fused attention dots ---------------

template<int K, int NN, int H, bool ATOMIC, typename AT>
__device__ void gemm_body(int bx, int M,
        const AT* __restrict__ A, const __half* __restrict__ Bp,
        const float* __restrict__ att_s, const float* __restrict__ att_d,
        float* __restrict__ as_, float* __restrict__ ad_,
        __half* __restrict__ Hout) {
    constexpr int KS = K >> 5;
    constexpr int CW = NN / 64;            // waves across columns
    constexpr int RW = 4 / CW;             // row-wave groups per block
    constexpr int C = NN / H;              // channels per head
    const int lane = threadIdx.x & 63;
    const int w = threadIdx.x >> 6;
    const int wr = w / CW;
    const int wc = w % CW;
    const int quad = lane >> 4;
    const int r16 = lane & 15;
    const int mBase = bx * (RW * 32) + wr * 32;
    const int nBase = wc * 64;
    const int head = nBase / C;

    f32x4 acc[2][4];
#pragma unroll
    for (int rt = 0; rt < 2; ++rt)
#pragma unroll
        for (int ct = 0; ct < 4; ++ct) acc[rt][ct] = (f32x4){0.f, 0.f, 0.f, 0.f};

#pragma unroll
    for (int ks = 0; ks < KS; ++ks) {
        f16x8 af[2];
#pragma unroll
        for (int rt = 0; rt < 2; ++rt) {
            int row = mBase + rt * 16 + r16;
            if (row < M) {
                af[rt] = loadAfrag(A + (size_t)row * K + ks * 32 + quad * 8);
            } else {
                af[rt] = (f16x8){0, 0, 0, 0, 0, 0, 0, 0};
            }
        }
        f16x8 bf[4];
#pragma unroll
        for (int ct = 0; ct < 4; ++ct) {
            int ctg = (nBase >> 4) + ct;
            size_t off = ((size_t)(ctg * KS + ks) * 64 + lane) * 8;
            bf[ct] = *(const f16x8*)(Bp + off);
        }
#pragma unroll
        for (int rt = 0; rt < 2; ++rt)
#pragma unroll
            for (int ct = 0; ct < 4; ++ct)
                acc[rt][ct] = __builtin_amdgcn_mfma_f32_16x16x32_f16(af[rt], bf[ct], acc[rt][ct], 0, 0, 0);
    }

    // store h (fp16); C/D layout: lane l reg r -> row=(l>>4)*4+r, col=l&15
#pragma unroll
    for (int rt = 0; rt < 2; ++rt)
#pragma unroll
        for (int ct = 0; ct < 4; ++ct) {
            int row0 = mBase + rt * 16 + quad * 4;
            int col = nBase + ct * 16 + r16;
#pragma unroll
            for (int r = 0; r < 4; ++r) {
                int row = row0 + r;
                if (row < M) Hout[(size_t)row * NN + col] = __float2half(acc[rt][ct][r]);
            }
        }

    // fused attention dots
    float attS[4], attD[4];
#pragma unroll
    for (int ct = 0; ct < 4; ++ct) {
        int cc = (nBase % C) + ct * 16 + r16;   // channel within head
        attS[ct] = att_s[head * C + cc];
        attD[ct] = att_d[head * C + cc];
    }
#pragma unroll
    for (int rt = 0; rt < 2; ++rt)
#pragma unroll
        for (int r = 0; r < 4; ++r) {
            float ps = 0.f, pd = 0.f;
#pragma unroll
            for (int ct = 0; ct < 4; ++ct) {
                ps += acc[rt][ct][r] * attS[ct];
                pd += acc[rt][ct][r] * attD[ct];
            }
#pragma unroll
            for (int off = 1; off < 16; off <<= 1) {
                ps += __shfl_xor(ps, off);
                pd += __shfl_xor(pd, off);
            }
            int row = mBase + rt * 16 + quad * 4 + r;
            if (r16 == 0 && row < M) {
                if (ATOMIC) {
                    atomicAdd(&as_[row * H + head], ps);
                    atomicAdd(&ad_[row * H + head], pd);
                } else {
                    as_[row * H + head] = ps;
                    ad_[row * H + head] = pd;
                }
            }
        }
}

// ---------------- layer-1: GEMM blocks first + scatter blocks last ---------

__global__ __launch_bounds__(256) void gemm1_scatter(
        int G1B, const int* __restrict__ ei, int E, int N,
        int* __restrict__ cnt, int* __restrict__ csr_src,
        const float* __restrict__ x, const __half* __restrict__ Bp,
        const float* __restrict__ att_s, const float* __restrict__ att_d,
        float* __restrict__ as_, float* __restrict__ ad_,
        __half* __restrict__ Hout) {
    if ((int)blockIdx.x < G1B) {
        gemm_body<128, 256, 4, false, float>(blockIdx.x, N, x, Bp,
                                             att_s, att_d, as_, ad_, Hout);
        return;
    }
    int e = (blockIdx.x - G1B) * 256 + threadIdx.x;
    if (e >= E) return;
    int s = ei[e], d = ei[E + e];
    int r = atomicAdd(&cnt[d], 1);
    if (r < 64) csr_src[(d << 6) + r] = s;
}

// ---------------- frozen R12 agg inner step --------------------------------

__device__ inline float edge_w(float a) {
    float e = a > 0.f ? a : NEG_SLOPE * a;
    return __expf(e);
}

template<int U, int HC, int H, int GRP>
__device__ inline void agg_step(int p, const int* __restrict__ csr_src,
                                const __half* __restrict__ h,
                                const float* __restrict__ as_, float adv,
                                int c0, int head, float* acc, float& den) {
    int srcv[U];
#pragma unroll
    for (int u = 0; u < U; ++u) srcv[u] = csr_src[p + u * GRP];
    float f[U][8];
#pragma unroll
    for (int u = 0; u < U; ++u) loadH8(f[u], h + (size_t)srcv[u] * HC + c0);
    float wv[U];
#pragma unroll
    for (int u = 0; u < U; ++u) wv[u] = edge_w(as_[srcv[u] * H + head] + adv);
#pragma unroll
    for (int u = 0; u < U; ++u) den += wv[u];
#pragma unroll
    for (int u = 0; u < U; ++u)
#pragma unroll
        for (int i = 0; i < 8; ++i) acc[i] += wv[u] * f[u][i];
}

// ---------------- fused agg1 + gemm2: one 64-node tile per block -----------
// Phase 1: 16 waves, wave wv aggregates nodes tile*64 + wv + 16k (k=0..3)
// with the frozen loop (LPE=32, GRP=2); ReLU'd x2 row -> LDS (fp16, row
// padded to 264 halves). Phase 2: gemm2 64x128 tile, A-frags from LDS,
// packed bp2 B; h2 + att dots (LDS-reduced as2/ad2, plain stores).

__global__ __launch_bounds__(1024) void agg1_gemm2(
        int N, const int* __restrict__ cnt, const int* __restrict__ csr_src,
        const __half* __restrict__ h1, const float* __restrict__ as1,
        const float* __restrict__ ad1, const float* __restrict__ b1,
        const __half* __restrict__ bp2, const float* __restrict__ att_s2,
        const float* __restrict__ att_d2,
        float* __restrict__ as2, float* __restrict__ ad2,
        __half* __restrict__ h2) {
    __shared__ __half x2t[64][264];      // padded: 528B row stride
    __shared__ float s_as[64], s_ad[64];
    const int tile = blockIdx.x;
    const int tid = threadIdx.x;
    if (tid < 64) { s_as[tid] = 0.f; s_ad[tid] = 0.f; }
    const int lane = tid & 63;
    const int wv = tid >> 6;             // 16 waves

    // ---- phase 1: aggregate 64 nodes ----
    {
        const int g = lane >> 5;         // edge slot (GRP=2)
        const int lq = lane & 31;
        const int c0 = lq * 8;
        const int head = c0 >> 6;        // 64 ch per head
#pragma unroll
        for (int k = 0; k < 4; ++k) {
            const int nl = wv + 16 * k;
            const int n = tile * 64 + nl;
            float o[8] = {0.f, 0.f, 0.f, 0.f, 0.f, 0.f, 0.f, 0.f};
            if (n < N) {
                const int s0 = n << 6;
                int deg = cnt[n]; if (deg > 64) deg = 64;
                const int s1 = s0 + deg;
                const float adv = ad1[n * 4 + head];
                float acc[8] = {};
                float den = 0.f;
                int p = s0 + g;
                for (; p + 6 < s1; p += 8)
                    agg_step<4, 256, 4, 2>(p, csr_src, h1, as1, adv, c0, head, acc, den);
                for (; p < s1; p += 2)
                    agg_step<1, 256, 4, 2>(p, csr_src, h1, as1, adv, c0, head, acc, den);
                den += __shfl_xor(den, 32);
#pragma unroll
                for (int i = 0; i < 8; ++i) acc[i] += __shfl_xor(acc[i], 32);
                float dinv = 1.0f / (den + 1e-16f);
#pragma unroll
                for (int i = 0; i < 8; ++i) {
                    float v = acc[i] * dinv + b1[c0 + i];
                    o[i] = v > 0.f ? v : 0.f;
                }
            }
            if (g == 0) {
                union { s16x8 raw; __half hv[8]; } u;
#pragma unroll
                for (int i = 0; i < 8; ++i) u.hv[i] = __float2half(o[i]);
                *(s16x8*)&x2t[nl][c0] = u.raw;
            }
        }
    }
    __syncthreads();

    // ---- phase 2: gemm2 (64 rows x 128 cols), A from LDS ----
    const int quad = lane >> 4;
    const int r16 = lane & 15;
    const int wr2 = wv & 3;              // 4 row groups x 16
    const int wc2 = wv >> 2;             // 4 col groups x 32
    f32x4 acc2[2];
    acc2[0] = (f32x4){0.f, 0.f, 0.f, 0.f};
    acc2[1] = (f32x4){0.f, 0.f, 0.f, 0.f};
#pragma unroll
    for (int ks = 0; ks < 8; ++ks) {
        f16x8 af = *(const f16x8*)&x2t[wr2 * 16 + r16][ks * 32 + quad * 8];
#pragma unroll
        for (int ct = 0; ct < 2; ++ct) {
            int ctg = wc2 * 2 + ct;
            f16x8 bf = *(const f16x8*)(bp2 + ((size_t)(ctg * 8 + ks) * 64 + lane) * 8);
            acc2[ct] = __builtin_amdgcn_mfma_f32_16x16x32_f16(af, bf, acc2[ct], 0, 0, 0);
        }
    }
    float attS[2], attD[2];
#pragma unroll
    for (int ct = 0; ct < 2; ++ct) {
        int col = wc2 * 32 + ct * 16 + r16;
        attS[ct] = att_s2[col];
        attD[ct] = att_d2[col];
    }
    const int row0 = wr2 * 16 + quad * 4;
#pragma unroll
    for (int r = 0; r < 4; ++r) {
        int grow = tile * 64 + row0 + r;
        if (grow < N) {
#pragma unroll
            for (int ct = 0; ct < 2; ++ct)
                h2[(size_t)grow * 128 + wc2 * 32 + ct * 16 + r16] =
                    __float2half(acc2[ct][r]);
        }
        float ps = acc2[0][r] * attS[0] + acc2[1][r] * attS[1];
        float pd = acc2[0][r] * attD[0] + acc2[1][r] * attD[1];
#pragma unroll
        for (int off = 1; off < 16; off <<= 1) {
            ps += __shfl_xor(ps, off);
            pd += __shfl_xor(pd, off);
        }
        if (r16 == 0 && grow < N) {
            atomicAdd(&s_as[row0 + r], ps);   // LDS atomics (cheap)
            atomicAdd(&s_ad[row0 + r], pd);
        }
    }
    __syncthreads();
    if (tid < 64) {
        int grow = tile * 64 + tid;
        if (grow < N) { as2[grow] = s_as[tid]; ad2[grow] = s_ad[tid]; }
    }
}

// ---------------- fused bucket softmax + aggregate (layer 2, frozen) -------

template<int HC, int H, bool F16OUT>
__global__ __launch_bounds__(256) void fused_agg(int N,
                                                 const int* __restrict__ cnt,
                                                 const int* __restrict__ csr_src,
                                                 const __half* __restrict__ h,
                                                 const float* __restrict__ as_,
                                                 const float* __restrict__ ad_,
                                                 const float* __restrict__ bias,
                                                 float* __restrict__ out,
                                                 __half* __restrict__ outh) {
    constexpr int LPE = HC / 8;          // lanes per edge (32 or 16)
    constexpr int GRP = 64 / LPE;        // concurrent edges per wave (2 or 4)
    constexpr int C = HC / H;
    const int n = blockIdx.x * 4 + (threadIdx.x >> 6);
    if (n >= N) return;
    const int lane = threadIdx.x & 63;
    const int g = lane / LPE;
    const int lq = lane % LPE;
    const int c0 = lq * 8;
    const int head = c0 / C;
    const int s0 = n << 6;
    int deg = cnt[n]; if (deg > 64) deg = 64;
    const int s1 = s0 + deg;
    const float adv = ad_[n * H + head];
    float acc[8] = {};
    float den = 0.f;
    int p = s0 + g;
    for (; p + 3 * GRP < s1; p += 4 * GRP)
        agg_step<4, HC, H, GRP>(p, csr_src, h, as_, adv, c0, head, acc, den);
    for (; p < s1; p += GRP)
        agg_step<1, HC, H, GRP>(p, csr_src, h, as_, adv, c0, head, acc, den);
#pragma unroll
    for (int off = LPE; off < 64; off <<= 1) {
        den += __shfl_xor(den, off);
#pragma unroll
        for (int i = 0; i < 8; ++i) acc[i] += __shfl_xor(acc[i], off);
    }
    if (g == 0) {
        float dinv = 1.0f / (den + 1e-16f);
        float o[8];
#pragma unroll
        for (int i = 0; i < 8; ++i) {
            float v = acc[i] * dinv + bias[c0 + i];
            o[i] = v > 0.f ? v : 0.f;
        }
        if (F16OUT) {
            union { s16x8 raw; __half hv[8]; } u;
#pragma unroll
            for (int i = 0; i < 8; ++i) u.hv[i] = __float2half(o[i]);
            *(s16x8*)(outh + (size_t)n * HC + c0) = u.raw;
        } else {
            float4 v0 = make_float4(o[0], o[1], o[2], o[3]);
            float4 v1 = make_float4(o[4], o[5], o[6], o[7]);
            *(float4*)(out + (size_t)n * HC + c0) = v0;
            *(float4*)(out + (size_t)n * HC + c0 + 4) = v1;
        }
    }
}

extern "C" void kernel_launch(void* const* d_in, const int* in_sizes, int n_in,
                              void* d_out, int out_size, void* d_ws, size_t ws_size,
                              hipStream_t stream) {
    const float* x      = (const float*)d_in[0];
    const int*   ei     = (const int*)d_in[1];
    const float* W1     = (const float*)d_in[2];
    const float* att_s1 = (const float*)d_in[3];
    const float* att_d1 = (const float*)d_in[4];
    const float* b1     = (const float*)d_in[5];
    const float* W2     = (const float*)d_in[6];
    const float* att_s2 = (const float*)d_in[7];
    const float* att_d2 = (const float*)d_in[8];
    const float* b2     = (const float*)d_in[9];
    float* out = (float*)d_out;

    const int N_ = in_sizes[0] / 128;   // 50000
    const int E_ = in_sizes[1] / 2;     // 800000

    // workspace layout
    __half* h1 = (__half*)d_ws;                              // N*256 fp16
    __half* h2 = h1 + (size_t)N_ * 256;                      // N*128 fp16
    __half* bp1 = h2 + (size_t)N_ * 128;                     // 32768 fp16
    __half* bp2 = bp1 + 32768;                               // 32768 fp16
    float* as1 = (float*)(bp2 + 32768);                      // N*4
    float* ad1 = as1 + (size_t)N_ * 4;                       // N*4
    int*   cnt = (int*)(ad1 + (size_t)N_ * 4);               // N (init by pack_prep)
    float* as2 = (float*)(cnt + N_);                         // N (plain stores)
    float* ad2 = as2 + N_;                                   // N (plain stores)
    int* csr_src = (int*)(ad2 + N_);                         // N*64 buckets

    int G1B = (N_ + 31) / 32;               // 1563 gemm1 blocks
    int SB  = (E_ + 255) / 256;             // 3125 scatter blocks (real edges)
    int TB  = (N_ + 63) / 64;               // 782 fused agg1+gemm2 tiles

    // pack W1/W2 + cnt=1 + self-loop slot (replaces memset dispatch)
    pack_prep<<<128, 256, 0, stream>>>(W1, bp1, W2, bp2, cnt, csr_src, N_);

    // ---- layer 1: GEMM blocks first + edge scatter blocks last ----
    gemm1_scatter<<<G1B + SB, 256, 0, stream>>>(
        G1B, ei, E_, N_, cnt, csr_src, x, bp1, att_s1, att_d1, as1, ad1, h1);

    // ---- fused: agg1 (LDS x2 tile) + gemm2 (256 -> 1x128) ----
    agg1_gemm2<<<TB, 1024, 0, stream>>>(
        N_, cnt, csr_src, h1, as1, ad1, b1,
        bp2, att_s2, att_d2, as2, ad2, h2);

    // ---- layer 2 aggregate ----
    fused_agg<128, 1, false><<<(N_ + 3) / 4, 256, 0, stream>>>(
        N_, cnt, csr_src, h2, as2, ad2, b2, out, nullptr);

    (void)n_in; (void)out_size; (void)ws_size;
}

// Round 11
// 270.081 us; speedup vs baseline: 1.0778x; 1.0778x over previous
//
#include <hip/hip_runtime.h>
#include <hip/hip_bf16.h>
#include <hip/hip_fp16.h>

// GAT 2-layer forward. N=50000, E=800000 (+N self loops).
// L1: 128 -> 4x64 concat 256, ReLU.  L2: 256 -> 128, ReLU.
// R1: fused CSR softmax+aggregate.  R8: fp16 MFMA GEMMs.  R5: att_dots in
// GEMM epilogue.  R6: 4 nodes/256-thd agg.
// FLOOR EVIDENCE (per-component, all counter-backed A/B):
//  - aggs ~64.5us each: R13/R14 ILP pipelining flat/negative; R15 traffic
//    -40% -> slower; R22 agg+gemm2 fusion -> slower (occupancy 68->34%).
//    Gather-issue/latency bound at ~3.7 TB/s random-line fabric rate.
//  - rank-atomics+scatter ~60us: R18-R21 insensitive to block ordering,
//    32x counter line padding, self-loop removal, coupled/decoupled forms.
//    Coherence-point RMW throughput floor.
//  - gemm1 ~20us / gemm2 ~28us / pack ~5us: off top-5; packed B required
//    (R17: in-register B-build from fp32 W -> 5x gemm slowdown).
// R23 = R21 restored: the empirical minimum (270.6us) of the explored
// structure space. Serial chain ~250us + gaps = ~270us.
// Pipeline: pack_prep -> gemm1(blocks first)+scatter(blocks last) -> agg1
// -> gemm2 -> agg2 (5 dispatches).

#define NEG_SLOPE 0.2f

typedef __attribute__((ext_vector_type(8))) _Float16 f16x8;  // 8 fp16 = 4 VGPRs
typedef __attribute__((ext_vector_type(8))) short s16x8;
typedef __attribute__((ext_vector_type(4))) float f32x4;

// 16B load of 8 fp16 -> 8 fp32
__device__ inline void loadH8(float* v, const __half* p) {
    union { s16x8 raw; __half2 h2[4]; } u;
    u.raw = *(const s16x8*)p;
#pragma unroll
    for (int i = 0; i < 4; ++i) {
        float2 f = __half22float2(u.h2[i]);
        v[2 * i] = f.x;
        v[2 * i + 1] = f.y;
    }
}

// A-fragment loaders: fp16 direct, or fp32 with in-register convert.
__device__ inline f16x8 loadAfrag(const __half* __restrict__ p) {
    return *(const f16x8*)p;
}
__device__ inline f16x8 loadAfrag(const float* __restrict__ p) {
    float4 a = *(const float4*)p;
    float4 b = *(const float4*)(p + 4);
    union { f16x8 v; __half hv[8]; } u;
    u.hv[0] = __float2half(a.x); u.hv[1] = __float2half(a.y);
    u.hv[2] = __float2half(a.z); u.hv[3] = __float2half(a.w);
    u.hv[4] = __float2half(b.x); u.hv[5] = __float2half(b.y);
    u.hv[6] = __float2half(b.z); u.hv[7] = __float2half(b.w);
    return u.v;
}

// ---------------- pack W1/W2 + init padded counters + self-loop slots ------
// B-frag (16x16x32): lane l holds B[k0 + (l>>4)*8 + j][n0 + (l&15)], j=0..7.

__device__ inline void pack_w_elem(const float* __restrict__ W, __half* __restrict__ bp,
                                   int K, int N, int tid) {
    int k = tid / N, n = tid - k * N;
    int ks = k >> 5, k5 = k & 31, quad = k5 >> 3, j = k5 & 7;
    int ct = n >> 4;
    int lane = quad * 16 + (n & 15);
    size_t idx = ((size_t)(ct * (K >> 5) + ks) * 64 + lane) * 8 + j;
    bp[idx] = __float2half(W[tid]);
}

// zp layout: [cntp : N*32 ints (one counter per 128B line)] [as2 : N] [ad2 : N]
// cnt counters init to 1 (self-loop pre-counted), everything else 0.
__global__ __launch_bounds__(256) void pack_prep(
        const float* __restrict__ W1, __half* __restrict__ bp1,
        const float* __restrict__ W2, __half* __restrict__ bp2,
        int* __restrict__ zp, int zn, int n32,
        int* __restrict__ csr_src, int N) {
    int tid = blockIdx.x * blockDim.x + threadIdx.x;     // 32768 threads
    if (tid < 128 * 256) pack_w_elem(W1, bp1, 128, 256, tid);
    if (tid < 256 * 128) pack_w_elem(W2, bp2, 256, 128, tid);
    for (int i = tid; i < zn; i += 32768)
        zp[i] = (i < n32 && (i & 31) == 0) ? 1 : 0;
    for (int n = tid; n < N; n += 32768)
        csr_src[n << 6] = n;                             // self-loop in slot 0
}

// ---------------- fp16 MFMA GEMM body + fused attention dots ---------------

template<int K, int NN, int H, bool ATOMIC, typename AT>
__device__ void gemm_body(int bx, int M,
        const AT* __restrict__ A, const __half* __restrict__ Bp,
        const float* __restrict__ att_s, const float* __restrict__ att_d,
        float* __restrict__ as_, float* __restrict__ ad_,
        __half* __restrict__ Hout) {
    constexpr int KS = K >> 5;
    constexpr int CW = NN / 64;            // waves across columns
    constexpr int RW = 4 / CW;             // row-wave groups per block
    constexpr int C = NN / H;              // channels per head
    const int lane = threadIdx.x & 63;
    const int w = threadIdx.x >> 6;
    const int wr = w / CW;
    const int wc = w % CW;
    const int quad = lane >> 4;
    const int r16 = lane & 15;
    const int mBase = bx * (RW * 32) + wr * 32;
    const int nBase = wc * 64;
    const int head = nBase / C;

    f32x4 acc[2][4];
#pragma unroll
    for (int rt = 0; rt < 2; ++rt)
#pragma unroll
        for (int ct = 0; ct < 4; ++ct) acc[rt][ct] = (f32x4){0.f, 0.f, 0.f, 0.f};

#pragma unroll
    for (int ks = 0; ks < KS; ++ks) {
        f16x8 af[2];
#pragma unroll
        for (int rt = 0; rt < 2; ++rt) {
            int row = mBase + rt * 16 + r16;
            if (row < M) {
                af[rt] = loadAfrag(A + (size_t)row * K + ks * 32 + quad * 8);
            } else {
                af[rt] = (f16x8){0, 0, 0, 0, 0, 0, 0, 0};
            }
        }
        f16x8 bf[4];
#pragma unroll
        for (int ct = 0; ct < 4; ++ct) {
            int ctg = (nBase >> 4) + ct;
            size_t off = ((size_t)(ctg * KS + ks) * 64 + lane) * 8;
            bf[ct] = *(const f16x8*)(Bp + off);
        }
#pragma unroll
        for (int rt = 0; rt < 2; ++rt)
#pragma unroll
            for (int ct = 0; ct < 4; ++ct)
                acc[rt][ct] = __builtin_amdgcn_mfma_f32_16x16x32_f16(af[rt], bf[ct], acc[rt][ct], 0, 0, 0);
    }

    // store h (fp16); C/D layout: lane l reg r -> row=(l>>4)*4+r, col=l&15
#pragma unroll
    for (int rt = 0; rt < 2; ++rt)
#pragma unroll
        for (int ct = 0; ct < 4; ++ct) {
            int row0 = mBase + rt * 16 + quad * 4;
            int col = nBase + ct * 16 + r16;
#pragma unroll
            for (int r = 0; r < 4; ++r) {
                int row = row0 + r;
                if (row < M) Hout[(size_t)row * NN + col] = __float2half(acc[rt][ct][r]);
            }
        }

    // fused attention dots
    float attS[4], attD[4];
#pragma unroll
    for (int ct = 0; ct < 4; ++ct) {
        int cc = (nBase % C) + ct * 16 + r16;   // channel within head
        attS[ct] = att_s[head * C + cc];
        attD[ct] = att_d[head * C + cc];
    }
#pragma unroll
    for (int rt = 0; rt < 2; ++rt)
#pragma unroll
        for (int r = 0; r < 4; ++r) {
            float ps = 0.f, pd = 0.f;
#pragma unroll
            for (int ct = 0; ct < 4; ++ct) {
                ps += acc[rt][ct][r] * attS[ct];
                pd += acc[rt][ct][r] * attD[ct];
            }
#pragma unroll
            for (int off = 1; off < 16; off <<= 1) {
                ps += __shfl_xor(ps, off);
                pd += __shfl_xor(pd, off);
            }
            int row = mBase + rt * 16 + quad * 4 + r;
            if (r16 == 0 && row < M) {
                if (ATOMIC) {
                    atomicAdd(&as_[row * H + head], ps);
                    atomicAdd(&ad_[row * H + head], pd);
                } else {
                    as_[row * H + head] = ps;
                    ad_[row * H + head] = pd;
                }
            }
        }
}

// ---------------- layer-1: GEMM blocks FIRST + scatter blocks LAST ---------
// Blocks [0, G1B): gemm1 (fp32 A from x, packed bp1). Blocks [G1B, +SB):
// one real edge/thread: r = atomicAdd(&cntp[d*32],1); csr_src[d*64+r] = s.

__global__ __launch_bounds__(256) void gemm1_scatter(
        int G1B, const int* __restrict__ ei, int E, int N,
        int* __restrict__ cntp, int* __restrict__ csr_src,
        const float* __restrict__ x, const __half* __restrict__ Bp,
        const float* __restrict__ att_s, const float* __restrict__ att_d,
        float* __restrict__ as_, float* __restrict__ ad_,
        __half* __restrict__ Hout) {
    if ((int)blockIdx.x < G1B) {
        gemm_body<128, 256, 4, false, float>(blockIdx.x, N, x, Bp,
                                             att_s, att_d, as_, ad_, Hout);
        return;
    }
    int e = (blockIdx.x - G1B) * 256 + threadIdx.x;
    if (e >= E) return;
    int s = ei[e], d = ei[E + e];
    int r = atomicAdd(&cntp[d << 5], 1);
    if (r < 64) csr_src[(d << 6) + r] = s;
}

__global__ __launch_bounds__(256) void gemm2_kernel(
        int M, const __half* __restrict__ A, const __half* __restrict__ Bp,
        const float* __restrict__ att_s, const float* __restrict__ att_d,
        float* __restrict__ as_, float* __restrict__ ad_,
        __half* __restrict__ Hout) {
    gemm_body<256, 128, 1, true, __half>(blockIdx.x, M, A, Bp,
                                         att_s, att_d, as_, ad_, Hout);
}

// ---------------- fused bucket softmax + aggregate (fp16 gather) -----------
// R12 structure (frozen; gather-issue/latency local floor). 256-thread block
// = 4 independent waves, wave w handles node blk*4+w. Bucket base = n*64,
// deg = cntp[n*32] (self-loop pre-counted in slot 0).

__device__ inline float edge_w(float a) {
    float e = a > 0.f ? a : NEG_SLOPE * a;
    return __expf(e);
}

template<int U, int HC, int H, int GRP>
__device__ inline void agg_step(int p, const int* __restrict__ csr_src,
                                const __half* __restrict__ h,
                                const float* __restrict__ as_, float adv,
                                int c0, int head, float* acc, float& den) {
    int srcv[U];
#pragma unroll
    for (int u = 0; u < U; ++u) srcv[u] = csr_src[p + u * GRP];
    float f[U][8];
#pragma unroll
    for (int u = 0; u < U; ++u) loadH8(f[u], h + (size_t)srcv[u] * HC + c0);
    float wv[U];
#pragma unroll
    for (int u = 0; u < U; ++u) wv[u] = edge_w(as_[srcv[u] * H + head] + adv);
#pragma unroll
    for (int u = 0; u < U; ++u) den += wv[u];
#pragma unroll
    for (int u = 0; u < U; ++u)
#pragma unroll
        for (int i = 0; i < 8; ++i) acc[i] += wv[u] * f[u][i];
}

template<int HC, int H, bool F16OUT>
__global__ __launch_bounds__(256) void fused_agg(int N,
                                                 const int* __restrict__ cntp,
                                                 const int* __restrict__ csr_src,
                                                 const __half* __restrict__ h,
                                                 const float* __restrict__ as_,
                                                 const float* __restrict__ ad_,
                                                 const float* __restrict__ bias,
                                                 float* __restrict__ out,
                                                 __half* __restrict__ outh) {
    constexpr int LPE = HC / 8;          // lanes per edge (32 or 16)
    constexpr int GRP = 64 / LPE;        // concurrent edges per wave (2 or 4)
    constexpr int C = HC / H;
    const int n = blockIdx.x * 4 + (threadIdx.x >> 6);
    if (n >= N) return;
    const int lane = threadIdx.x & 63;
    const int g = lane / LPE;
    const int lq = lane % LPE;
    const int c0 = lq * 8;
    const int head = c0 / C;
    const int s0 = n << 6;
    int deg = cntp[n << 5]; if (deg > 64) deg = 64;
    const int s1 = s0 + deg;
    const float adv = ad_[n * H + head];
    float acc[8] = {};
    float den = 0.f;
    int p = s0 + g;
    for (; p + 3 * GRP < s1; p += 4 * GRP)
        agg_step<4, HC, H, GRP>(p, csr_src, h, as_, adv, c0, head, acc, den);
    for (; p < s1; p += GRP)
        agg_step<1, HC, H, GRP>(p, csr_src, h, as_, adv, c0, head, acc, den);
#pragma unroll
    for (int off = LPE; off < 64; off <<= 1) {
        den += __shfl_xor(den, off);
#pragma unroll
        for (int i = 0; i < 8; ++i) acc[i] += __shfl_xor(acc[i], off);
    }
    if (g == 0) {
        float dinv = 1.0f / (den + 1e-16f);
        float o[8];
#pragma unroll
        for (int i = 0; i < 8; ++i) {
            float v = acc[i] * dinv + bias[c0 + i];
            o[i] = v > 0.f ? v : 0.f;
        }
        if (F16OUT) {
            union { s16x8 raw; __half hv[8]; } u;
#pragma unroll
            for (int i = 0; i < 8; ++i) u.hv[i] = __float2half(o[i]);
            *(s16x8*)(outh + (size_t)n * HC + c0) = u.raw;
        } else {
            float4 v0 = make_float4(o[0], o[1], o[2], o[3]);
            float4 v1 = make_float4(o[4], o[5], o[6], o[7]);
            *(float4*)(out + (size_t)n * HC + c0) = v0;
            *(float4*)(out + (size_t)n * HC + c0 + 4) = v1;
        }
    }
}

extern "C" void kernel_launch(void* const* d_in, const int* in_sizes, int n_in,
                              void* d_out, int out_size, void* d_ws, size_t ws_size,
                              hipStream_t stream) {
    const float* x      = (const float*)d_in[0];
    const int*   ei     = (const int*)d_in[1];
    const float* W1     = (const float*)d_in[2];
    const float* att_s1 = (const float*)d_in[3];
    const float* att_d1 = (const float*)d_in[4];
    const float* b1     = (const float*)d_in[5];
    const float* W2     = (const float*)d_in[6];
    const float* att_s2 = (const float*)d_in[7];
    const float* att_d2 = (const float*)d_in[8];
    const float* b2     = (const float*)d_in[9];
    float* out = (float*)d_out;

    const int N_ = in_sizes[0] / 128;   // 50000
    const int E_ = in_sizes[1] / 2;     // 800000

    // workspace layout
    __half* h1 = (__half*)d_ws;                              // N*256 fp16 (also h2)
    __half* x2 = h1 + (size_t)N_ * 256;                      // N*256 fp16
    __half* bp1 = x2 + (size_t)N_ * 256;                     // 32768 fp16
    __half* bp2 = bp1 + 32768;                               // 32768 fp16
    float* as1 = (float*)(bp2 + 32768);                      // N*4
    float* ad1 = as1 + (size_t)N_ * 4;                       // N*4
    // ---- init region (written by pack_prep): cntp | as2 | ad2
    int*   cntp = (int*)(ad1 + (size_t)N_ * 4);              // N*32 (128B/counter)
    float* as2  = (float*)(cntp + (size_t)N_ * 32);          // N
    float* ad2  = as2 + N_;                                  // N
    int zn  = N_ * 32 + 2 * N_;
    int n32 = N_ * 32;
    // ---- end init region
    int* csr_src = (int*)(ad2 + N_);                         // N*64 buckets

    int G1B = (N_ + 31) / 32;               // 1563 gemm1 blocks
    int SB  = (E_ + 255) / 256;             // 3125 scatter blocks (real edges)
    int G2B = (N_ + 63) / 64;               // 782 gemm2 blocks

    // pack W1/W2 + init counters (=1, self-loop) + self-loop slot stores
    pack_prep<<<128, 256, 0, stream>>>(W1, bp1, W2, bp2,
                                       cntp, zn, n32, csr_src, N_);

    // ---- layer 1: GEMM blocks first + edge scatter blocks last ----
    gemm1_scatter<<<G1B + SB, 256, 0, stream>>>(
        G1B, ei, E_, N_, cntp, csr_src, x, bp1, att_s1, att_d1, as1, ad1, h1);
    fused_agg<256, 4, true><<<(N_ + 3) / 4, 256, 0, stream>>>(
        N_, cntp, csr_src, h1, as1, ad1, b1, nullptr, x2);

    // ---- layer 2: 256 -> 1x128 ----
    __half* h2 = h1;  // reuse
    gemm2_kernel<<<G2B, 256, 0, stream>>>(
        N_, x2, bp2, att_s2, att_d2, as2, ad2, h2);
    fused_agg<128, 1, false><<<(N_ + 3) / 4, 256, 0, stream>>>(
        N_, cntp, csr_src, h2, as2, ad2, b2, out, nullptr);

    (void)n_in; (void)out_size; (void)ws_size;
}